// Round 7
// baseline (89.093 us; speedup 1.0000x reference)
//
#include <hip/hip_runtime.h>

// Embedder: counts = scatter_add(one_hot(tokens)) -> (B, DEPTH) float32
// B=1024, S=200, DEPTH=100000. Output = 409.6 MB -> pure write-BW bound.
//
// One block per ROW (1024 blocks = exactly 4/CU, all co-resident -> single
// generation, overhead paid once per 400 KB row, not once per 20-50 KB
// segment like rounds 2/3/5):
//   1. load the row's 200 (token,value) pairs
//   2. counting-sort into 98 buckets (windows of 1024 floats, w = t>>10)
//      via LDS atomics + 7-step Hillis-Steele scan  (~2500 cy, once)
//   3. ONE barrier, then a barrier-free store loop: 98 iterations, each
//      thread builds its float4 in registers (zeros + predicated adds from
//      the window's ~2 bucket entries, uniform-address LDS broadcasts) and
//      issues one global_store_dwordx4. No zero pass, no global RMW, no
//      vmcnt(0) drains anywhere in the stream.

#define EMB_DEPTH 100000
#define EMB_SEQ   200
#define NW        98            // ceil(100000 / 1024) windows per row
#define NF4       25000         // float4 per row
#define NITER     98            // ceil(25000 / 256)

__global__ __launch_bounds__(256) void embedder_row_kernel(
    const int*   __restrict__ tokens,     // (B, S) int32
    const float* __restrict__ on_values,  // (B, S) float32
    float*       __restrict__ out)        // (B, DEPTH) float32
{
    __shared__ int  bcnt[128];           // bucket counts (NW=98, padded)
    __shared__ int  scan[2][128];        // Hillis-Steele ping-pong
    __shared__ int  foff[NW + 2];        // exclusive offsets, foff[NW]=200
    __shared__ int2 bpack[EMB_SEQ];      // bucket-sorted (token, value bits)

    const int tid = threadIdx.x;
    const int b   = blockIdx.x;

    // --- load my (token, value); latency hides under the setup below ---
    int   t = 0;
    float v = 0.0f;
    if (tid < EMB_SEQ) {
        t = tokens[(size_t)b * EMB_SEQ + tid];
        v = on_values[(size_t)b * EMB_SEQ + tid];
    }

    if (tid < 128) bcnt[tid] = 0;
    __syncthreads();

    // --- count ---
    int w = 0, rank = 0;
    if (tid < EMB_SEQ) {
        w    = t >> 10;                       // window of 1024 floats
        rank = atomicAdd(&bcnt[w], 1);        // ds_add_rtn_u32
    }
    __syncthreads();

    // --- inclusive scan over 128 entries (7 steps) ---
    if (tid < 128) scan[0][tid] = bcnt[tid];
    __syncthreads();
    int src = 0;
    for (int d = 1; d < 128; d <<= 1) {
        if (tid < 128) {
            int val = scan[src][tid];
            if (tid >= d) val += scan[src][tid - d];
            scan[src ^ 1][tid] = val;
        }
        __syncthreads();
        src ^= 1;
    }
    // exclusive offsets: foff[j] = inclusive[j-1], foff[0] = 0
    if (tid < NW) foff[tid + 1] = scan[src][tid];
    if (tid == 0) foff[0] = 0;
    __syncthreads();

    // --- scatter into bucket-sorted order ---
    if (tid < EMB_SEQ) {
        bpack[foff[w] + rank] = make_int2(t, __float_as_int(v));
    }
    __syncthreads();

    // --- barrier-free merged write stream: 98 x global_store_dwordx4 ---
    float4* out4 = reinterpret_cast<float4*>(out + (size_t)b * EMB_DEPTH);
    for (int j = 0; j < NITER; ++j) {
        const int f4 = j * 256 + tid;         // my float4 index this window
        if (f4 >= NF4) break;                 // last iter: tid >= 168 done
        float4 r = make_float4(0.0f, 0.0f, 0.0f, 0.0f);
        const int s = foff[j];                // uniform across block
        const int e = foff[j + 1];
        for (int k = s; k < e; ++k) {         // avg 2 entries per window
            const int2 p = bpack[k];          // same-addr broadcast read
            if ((p.x >> 2) == f4) {           // token lands in my float4?
                const float vv = __int_as_float(p.y);
                const int   c  = p.x & 3;
                r.x += (c == 0) ? vv : 0.0f;
                r.y += (c == 1) ? vv : 0.0f;
                r.z += (c == 2) ? vv : 0.0f;
                r.w += (c == 3) ? vv : 0.0f;
            }
        }
        out4[f4] = r;
    }
}

extern "C" void kernel_launch(void* const* d_in, const int* in_sizes, int n_in,
                              void* d_out, int out_size, void* d_ws, size_t ws_size,
                              hipStream_t stream) {
    const int*   tokens    = (const int*)  d_in[0];
    const float* on_values = (const float*)d_in[1];
    float*       out       = (float*)      d_out;

    const int B = in_sizes[0] / EMB_SEQ;      // 1024
    embedder_row_kernel<<<B, 256, 0, stream>>>(tokens, on_values, out);
}